// Round 8
// baseline (265.955 us; speedup 1.0000x reference)
//
#include <hip/hip_runtime.h>

// GQA_22436909154699: softmax over a size-1 axis == 1.0, so the reference
// reduces to  out[bl, g*512+h*64+d] = (x @ Wkv + bkv)[bl, g*128+64+d].
// => one (16384 x 2048) @ (2048 x 256) GEMM (v-cols only) + broadcast x8.
// R15: DRAM-granularity fix for the x read. Evidence: across R7/R10/R12/R13
// the x HBM read rate pins at ~2.0 TB/s; A staging reads x in 128-B
// granules from 16K concurrent row-streams -> ~1 DRAM ACT per 128 B line
// (ACT-limited ~2 TB/s). m97 pushed 13.7 TB/s through the same
// global_load_lds path (L2-hot), so the DMA engine isn't the cap. Change
// (vs R13, single-variable): A staged in k-stripes of 128 floats -- each
// DMA reads a CONTIGUOUS 512-B row chunk (4x coarser). A = 2 x 32 KB
// stripe buffers; B = R13's exact 4-deep BK=32 ring; LDS 128 KB, 1 blk/CU;
// same 64 barriers, same reads->stage->MFMA order; counted per-slab waits
// vmcnt(8/16/16/8) derived from the in-order DMA stream, never drained.
// A swizzle: slot ^= (row&7), applied both-sides (pre-swizzled source +
// swizzled ds_read); XOR permutes lanes within the same 512 B burst.

#define EMBED 2048
#define SV 272  // epilogue LDS row stride in floats

typedef _Float16 half8 __attribute__((ext_vector_type(8)));
typedef _Float16 half4v __attribute__((ext_vector_type(4)));
typedef float f32x4 __attribute__((ext_vector_type(4)));

#define GLOAD16(g, l)                                                      \
  __builtin_amdgcn_global_load_lds(                                        \
      (const __attribute__((address_space(1))) void*)(g),                  \
      (__attribute__((address_space(3))) void*)(l), 16, 0, 0)

// ---- pre-pass: Bt[n][k] (f16) = Wkv[k][vcol(n)], vcol(n)=(n>>6)*128+64+(n&63)
__global__ __launch_bounds__(256) void prep_b(const float* __restrict__ Wkv,
                                              _Float16* __restrict__ Bt) {
  const int t = threadIdx.x;
  const int kb = blockIdx.x * 4;  // 512 blocks cover k = 0..2047
  const int vcol = ((t >> 6) * 128) + 64 + (t & 63);
  float v[4];
#pragma unroll
  for (int i = 0; i < 4; ++i) v[i] = Wkv[(size_t)(kb + i) * 512 + vcol];
  half4v h;
#pragma unroll
  for (int i = 0; i < 4; ++i) h[i] = (_Float16)v[i];
  *(half4v*)&Bt[(size_t)t * EMBED + kb] = h;
}

// ---- main: 256 blocks, block = 64 rows x 256 cols, 4 waves (64 n-cols each)
__global__ __launch_bounds__(256) void gqa_main(
    const float* __restrict__ x, const _Float16* __restrict__ Bt,
    const float* __restrict__ bkv, float* __restrict__ out) {
  // A: 2 stripe bufs x 32 KB (64 rows x 512 B) ; B: 4 slab bufs x 16 KB
  __shared__ __align__(16) char smem[2 * 32768 + 4 * 16384];  // 128 KB
  char* const Ab = smem;
  char* const Bb = smem + 2 * 32768;
  float* const Vs = (float*)smem;  // epilogue overlay [8][SV] = 8.7 KB

  const int tid = threadIdx.x;
  const int w = tid >> 6;    // wave: n-cols [w*64, w*64+64)
  const int lane = tid & 63;
  const int lm = lane & 15;
  const int lq = lane >> 4;
  const int lm7 = lm & 7;
  const int row0 = blockIdx.x * 64;

  // ---- A staging: per stripe, wave w covers rows w*16..w*16+15 with 8
  // instrs; instr i = rows {w*16+i*2, +1} (lane>>5 picks the row), each a
  // contiguous 512-B chunk, lanes XOR-permuted inside it by (row&7)<<4.
  const int arl = lane >> 5;           // row within pair
  const int aslot16 = (lane & 31) * 16;
  const char* axrowp =
      (const char*)x + (size_t)(row0 + w * 16 + arl) * (EMBED * 4);
  const int awdst = w * 8192;          // + i*1024 (2 rows x 512 B)

#define ASTAGE(ba, sidx)                                                   \
  {                                                                        \
    const size_t so_ = (size_t)(sidx) * 512;                               \
    _Pragma("unroll") for (int i_ = 0; i_ < 8; ++i_) {                     \
      GLOAD16(axrowp + (size_t)i_ * 2 * (EMBED * 4) + so_ +                \
                  (aslot16 ^ ((((i_ * 2) + arl) & 7) << 4)),               \
              Ab + (ba) * 32768 + awdst + i_ * 1024);                      \
    }                                                                      \
  }

  // ---- B staging: byte-identical to R12/R13 (BK=32, 64-B rows, swizzled)
  const int bcol = (((lane & 3) ^ ((lane >> 3) & 3)) << 4);
  const char* bsrc = (const char*)Bt +
      (size_t)(w * 64 + (lane >> 2)) * (EMBED * 2) + bcol;
  const int bdst0 = (w * 64) * 64;

#define BSTAGE(bb, t)                                                      \
  {                                                                        \
    const char* bs_ = bsrc + (size_t)(t) * 64;                             \
    char* bd_ = Bb + (bb) * 16384 + bdst0;                                 \
    GLOAD16(bs_, bd_);                                                     \
    GLOAD16(bs_ + (size_t)16 * EMBED * 2, bd_ + 1024);                     \
    GLOAD16(bs_ + (size_t)32 * EMBED * 2, bd_ + 2048);                     \
    GLOAD16(bs_ + (size_t)48 * EMBED * 2, bd_ + 3072);                     \
  }

  // ---- fragment reads
  // A: addr = ba*32768 + (mi*16+lm)*512 + j*128 + ((lq*2+t)^lm7)*16
  const char* ard = Ab + lm * 512;
  const int alq0 = ((lq * 2) ^ lm7) << 4;
  const int alq1 = ((lq * 2 + 1) ^ lm7) << 4;
  // B: identical to R13
  const int brswz = ((lm >> 1) & 3) << 4;
  const char* brd = Bb + (w * 64 + lm) * 64 + ((lq << 4) ^ brswz);

#define LOADFRAG(BA, BB, J)                                                \
  {                                                                        \
    _Pragma("unroll") for (int ni = 0; ni < 4; ++ni)                       \
        bfr_[ni] = *(const half8*)(brd + (BB) * 16384 + ni * 1024);        \
    _Pragma("unroll") for (int mi = 0; mi < 4; ++mi) {                     \
      a0r_[mi] =                                                           \
          *(const f32x4*)(ard + (BA) * 32768 + mi * 8192 + (J) * 128 + alq0); \
      a1r_[mi] =                                                           \
          *(const f32x4*)(ard + (BA) * 32768 + mi * 8192 + (J) * 128 + alq1); \
    }                                                                      \
  }
#define MFMAFRAG()                                                         \
  _Pragma("unroll") for (int mi = 0; mi < 4; ++mi) {                       \
    half8 af_;                                                             \
    _Pragma("unroll") for (int j = 0; j < 4; ++j)                          \
        af_[j] = (_Float16)a0r_[mi][j];                                    \
    _Pragma("unroll") for (int j = 0; j < 4; ++j)                          \
        af_[4 + j] = (_Float16)a1r_[mi][j];                                \
    _Pragma("unroll") for (int ni = 0; ni < 4; ++ni)                       \
        acc[mi][ni] = __builtin_amdgcn_mfma_f32_16x16x32_f16(              \
            af_, bfr_[ni], acc[mi][ni], 0, 0, 0);                          \
  }

  f32x4 acc[4][4] = {};

  // prologue: A stripe 0; B slabs 0,1,2. (20 DMAs/wave outstanding)
  ASTAGE(0, 0);
  BSTAGE(0, 0);
  BSTAGE(1, 1);
  BSTAGE(2, 2);

  // Per stripe s (4 slabs t=4s+j, B buf == j since 4s%4==0):
  //  j=0: vmcnt(8)  -> bar -> frags -> ASTAGE(s+1) + BSTAGE(buf3, t+3) -> MFMA
  //  j=1: vmcnt(16) -> bar -> frags -> BSTAGE(buf0, t+3) -> MFMA
  //  j=2: vmcnt(16) -> bar -> frags -> BSTAGE(buf1, t+3) -> MFMA
  //  j=3: vmcnt(8)  -> bar -> frags -> BSTAGE(buf2, t+3) -> MFMA
  // Wait constants from the in-order DMA stream (A issued at stripe start):
  // outstanding-after-the-needed-slab = 8,16,16,8. Never drained in-loop.
  // Tail junk: A(16)->re-stage 15 into buf0; B(>63)->63 into retired bufs.
#define SLAB(BA, BN, S, J, BBUF, BSTG, WAITM)                              \
  {                                                                        \
    asm volatile("s_waitcnt vmcnt(" WAITM ")" ::: "memory");               \
    __builtin_amdgcn_s_barrier();                                          \
    f32x4 a0r_[4], a1r_[4];                                                \
    half8 bfr_[4];                                                         \
    LOADFRAG(BA, BBUF, J);                                                 \
    if ((J) == 0) {                                                        \
      const int sn_ = (S) + 1 < 16 ? (S) + 1 : 15;                         \
      ASTAGE(BN, sn_);                                                     \
    }                                                                      \
    {                                                                      \
      const int bt_ = 4 * (S) + 3 + (J);                                   \
      BSTAGE(BSTG, bt_ < 64 ? bt_ : 63);                                   \
    }                                                                      \
    MFMAFRAG();                                                            \
  }
#define STRIPE(S, BA, BN)                                                  \
  SLAB(BA, BN, S, 0, 0, 3, "8")                                            \
  SLAB(BA, BN, S, 1, 1, 0, "16")                                           \
  SLAB(BA, BN, S, 2, 2, 1, "16")                                           \
  SLAB(BA, BN, S, 3, 3, 2, "8")

  for (int ss = 0; ss < 16; ss += 2) {
    STRIPE(ss, 0, 1)
    STRIPE(ss + 1, 1, 0)
  }
#undef STRIPE
#undef SLAB

  // epilogue: drain junk DMAs before overlaying smem with Vs
  asm volatile("s_waitcnt vmcnt(0)" ::: "memory");
  __syncthreads();

  float bias[4];
#pragma unroll
  for (int ni = 0; ni < 4; ++ni) bias[ni] = bkv[w * 128 + 64 + ni * 16 + lm];

  // 8 chunks of 8 rows: acc -> Vs (v-cols 0..255) -> broadcast x8 coalesced
#pragma unroll
  for (int c = 0; c < 8; ++c) {
    const int mi = c >> 1;  // compile-time after unroll
    if ((lq >> 1) == (c & 1)) {
#pragma unroll
      for (int ni = 0; ni < 4; ++ni) {
        const int n = w * 64 + ni * 16 + lm;
        f32x4 v = acc[mi][ni];
#pragma unroll
        for (int r = 0; r < 4; ++r)
          Vs[((lq & 1) * 4 + r) * SV + n] = v[r] + bias[ni];
      }
    }
    __syncthreads();
    f32x4* out4 = (f32x4*)(out + (size_t)(row0 + c * 8) * EMBED);
#pragma unroll 4
    for (int i = 0; i < 16; ++i) {
      const int f = i * 256 + tid;  // 8 rows x 512 float4
      const int row = f >> 9;
      const int c4 = f & 511;
      const int grp = c4 >> 7;
      const int d4 = c4 & 15;
      out4[(size_t)row * 512 + c4] =
          *(const f32x4*)&Vs[row * SV + grp * 64 + d4 * 4];
    }
    __syncthreads();
  }
}

extern "C" void kernel_launch(void* const* d_in, const int* in_sizes, int n_in,
                              void* d_out, int out_size, void* d_ws, size_t ws_size,
                              hipStream_t stream) {
  const float* x = (const float*)d_in[0];
  // d_in[1] = Wq, d_in[2] = bq : dead code (softmax over size-1 axis == 1)
  const float* Wkv = (const float*)d_in[3];
  const float* bkv = (const float*)d_in[4];
  float* out = (float*)d_out;
  _Float16* Bt = (_Float16*)d_ws;  // 256*2048 f16 = 1 MB scratch

  prep_b<<<512, 256, 0, stream>>>(Wkv, Bt);
  gqa_main<<<256, 256, 0, stream>>>(x, Bt, bkv, out);
}